// Round 21
// baseline (350.791 us; speedup 1.0000x reference)
//
#include <hip/hip_runtime.h>
#include <hip/hip_bf16.h>

typedef __attribute__((ext_vector_type(8))) short short8;   // 8 bf16 (4 VGPRs)
typedef __attribute__((ext_vector_type(4))) float f32x4;    // MFMA 16x16 C/D
typedef __attribute__((ext_vector_type(16))) float f32x16;  // MFMA 32x32 C/D

#define NB 8
#define NC 256
#define NN 4096
#define ND 32
#define NCH 16   // attn j-chunks of 256
#define LOG2E 1.44269504088896340736f

// attn P tile [2][128][256] ushort, 16B-slot XOR swizzle (validated R8/R10).
#define PIDX(row, col) (((row) << 8) + ((col) ^ (((row) & 15) << 3)))

static __device__ __forceinline__ ushort f2bf(float f) {
  __hip_bfloat16 h = __float2bfloat16(f);
  return reinterpret_cast<ushort&>(h);
}
static __device__ __forceinline__ float bf2f(ushort u) {
  const uint v = ((uint)u) << 16;
  return __builtin_bit_cast(float, v);
}

// ---------------------------------------------------------------------------
// Projection via MFMA — R16 VERBATIM (validated: fast, absmax 0.125).
// ---------------------------------------------------------------------------
#define LDW 264   // Ws row stride (ushorts)
#define LDX 40    // Xs row stride (ushorts)
#define LDO 136   // Os row stride (ushorts)

__global__ __launch_bounds__(256, 2)
void proj_kernel(const float* __restrict__ x,
                 const float* __restrict__ wq, const float* __restrict__ bq,
                 const float* __restrict__ wk, const float* __restrict__ bk,
                 const float* __restrict__ wv, const float* __restrict__ bv,
                 ushort* __restrict__ qk, ushort* __restrict__ vt) {
  __shared__ __align__(16) ushort Ws[2][64 * LDW];   // 67.6 KB
  __shared__ __align__(16) ushort Xs[128 * LDX];     // 10.2 KB

  const int n0 = blockIdx.x * 128;
  const int o0 = blockIdx.y * 64;
  const int b  = blockIdx.z;
  const int t  = threadIdx.x;
  const int w  = t >> 6;
  const int lane = t & 63;
  const int g16  = lane >> 4;
  const int c16  = lane & 15;

  {
    const int o  = t >> 2;
    const int cb = (t & 3) * 64;
    const int oa = o0 + o;
    const float* wrow;
    float scale = 1.0f;
    if (oa < 32)       { wrow = wq + (size_t)oa * NC; scale = LOG2E; }
    else if (oa < 64)  { wrow = wk + (size_t)(oa - 32) * NC; }
    else               { wrow = wv + (size_t)(oa - 64) * NC; }
#pragma unroll
    for (int cc = 0; cc < 64; cc += 8) {
      const float4 f0 = *(const float4*)(wrow + cb + cc);
      const float4 f1 = *(const float4*)(wrow + cb + cc + 4);
      float v[8] = {f0.x, f0.y, f0.z, f0.w, f1.x, f1.y, f1.z, f1.w};
      union { ushort u[8]; uint4 q; } hi, lo;
#pragma unroll
      for (int e = 0; e < 8; ++e) {
        const float s = v[e] * scale;
        const ushort h = f2bf(s);
        hi.u[e] = h;
        lo.u[e] = f2bf(s - bf2f(h));
      }
      *(uint4*)&Ws[0][o * LDW + cb + cc] = hi.q;
      *(uint4*)&Ws[1][o * LDW + cb + cc] = lo.q;
    }
  }

  f32x4 acc[8];
#pragma unroll
  for (int nt = 0; nt < 8; ++nt)
#pragma unroll
    for (int r = 0; r < 4; ++r) acc[nt][r] = 0.f;

  const int s_cc = w * 8 + (lane >> 3);
  const int s_nb = (lane & 7) * 4;

  for (int c0 = 0; c0 < NC; c0 += 32) {
    __syncthreads();
    {
      const float* xsrc = x + ((size_t)(b * NC + c0 + s_cc)) * NN + n0 + s_nb;
#pragma unroll
      for (int it = 0; it < 4; ++it) {
        const float4 f = *(const float4*)(xsrc + it * 32);
        const int n = s_nb + it * 32;
        Xs[(n + 0) * LDX + s_cc] = f2bf(f.x);
        Xs[(n + 1) * LDX + s_cc] = f2bf(f.y);
        Xs[(n + 2) * LDX + s_cc] = f2bf(f.z);
        Xs[(n + 3) * LDX + s_cc] = f2bf(f.w);
      }
    }
    __syncthreads();

    const short8 ah = *(const short8*)&Ws[0][(w * 16 + c16) * LDW + c0 + g16 * 8];
    const short8 al = *(const short8*)&Ws[1][(w * 16 + c16) * LDW + c0 + g16 * 8];
#pragma unroll
    for (int nt = 0; nt < 8; ++nt) {
      const short8 bf = *(const short8*)&Xs[(nt * 16 + c16) * LDX + g16 * 8];
      acc[nt] = __builtin_amdgcn_mfma_f32_16x16x32_bf16(ah, bf, acc[nt], 0, 0, 0);
      acc[nt] = __builtin_amdgcn_mfma_f32_16x16x32_bf16(al, bf, acc[nt], 0, 0, 0);
    }
  }

  if (blockIdx.y == 0) {
    float bb[4];
#pragma unroll
    for (int r = 0; r < 4; ++r) {
      const int o = w * 16 + g16 * 4 + r;
      bb[r] = (o < 32) ? bq[o] * LOG2E : bk[o - 32];
    }
#pragma unroll
    for (int nt = 0; nt < 8; ++nt) {
      union { ushort u[4]; uint2 v; } pk;
#pragma unroll
      for (int r = 0; r < 4; ++r) pk.u[r] = f2bf(acc[nt][r] + bb[r]);
      const int n = n0 + nt * 16 + c16;
      *(uint2*)(qk + ((size_t)(b * NN + n)) * 64 + w * 16 + g16 * 4) = pk.v;
    }
  } else {
    const int ch0 = o0 - 64;
    float bb[4];
#pragma unroll
    for (int r = 0; r < 4; ++r) bb[r] = bv[ch0 + w * 16 + g16 * 4 + r];
    __syncthreads();
    ushort* Os = &Ws[0][0];
#pragma unroll
    for (int nt = 0; nt < 8; ++nt) {
#pragma unroll
      for (int r = 0; r < 4; ++r)
        Os[(w * 16 + g16 * 4 + r) * LDO + nt * 16 + c16] =
            f2bf(acc[nt][r] + bb[r]);
    }
    __syncthreads();
    const int chl = t >> 2;
    const int nb  = (t & 3) * 32;
    ushort* dst = vt + ((size_t)(b * NC + ch0 + chl)) * NN + n0 + nb;
#pragma unroll
    for (int k = 0; k < 4; ++k)
      *(uint4*)(dst + k * 8) = *(const uint4*)&Os[chl * LDO + nb + k * 8];
  }
}

// ---------------------------------------------------------------------------
// Flash attention: R18 12-wave structure + register-neutral rotation
// pipelining. 256 blocks x 768 threads, 3 waves/SIMD (1 S + 2 PV).
//  Waves 0-3  (S): rows w*32..+32. kf[8] software rotation: each S_JT(kf[jt])
//    is immediately followed by reloading kf[jt] with the fragment needed 8
//    steps later (half0 -> half1 -> next chunk's half0, wrapped on the last
//    chunk). ~7 S_JT (~600cy) of cover per reload -> no exposed K waits.
//    Cross-barrier reloads drain at __syncthreads, hidden by S's early
//    arrival (S work < PV work).
//  Waves 4-11 (PV): 32 ch x 128 rows (OA[4] = 64 AGPR). 2-slot V rotation
//    refilled 2 STEPS AHEAD (copy slot, refill with wrapped uniform offset);
//    slots persist across chunks (steps 14/15 preload next chunk's 0/1);
//    iv==0 preloads the first pair. ~300cy cover ~= L2 latency.
// Zero new register names vs R18 -> no spill expected.
// ---------------------------------------------------------------------------
__global__ __launch_bounds__(768, 3)
void attn_kernel(const ushort* __restrict__ qk, const ushort* __restrict__ vt,
                 const float* __restrict__ x, const float* __restrict__ gamma,
                 float* __restrict__ out) {
  __shared__ __align__(16) ushort P[2][128 * 256];   // 128 KB, swizzled
  __shared__ __align__(16) float lL[128];

  const int lin  = blockIdx.x;
  const int b    = lin & 7;              // XCD swizzle: batch per XCD L2
  const int i0   = (lin >> 3) * 128;
  const int t    = threadIdx.x;
  const int w    = t >> 6;               // 0..11
  const int lane = t & 63;
  const int g16  = lane >> 4;
  const int c16  = lane & 15;
  const int l5   = lane >> 5;
  const int c32  = lane & 31;

  const f32x4 zero = {0.f, 0.f, 0.f, 0.f};
  const bool isS = (w < 4);

  // ---- S state (waves 0-3): 32 q-rows each ----
  const int prow0 = w * 32 + c16;
  const int prow1 = prow0 + 16;
  short8 qf0, qf1;
  short8 kf[8];
  float lp0 = 0.f, lp1 = 0.f;
  const ushort* kbase = qk + ((size_t)b * NN) * 64 + 32 + g16 * 8;

#define S_JT(KF, COL)                                                         \
  do {                                                                        \
    const f32x4 s0 = __builtin_amdgcn_mfma_f32_16x16x32_bf16(KF, qf0, zero,   \
                                                             0, 0, 0);        \
    const f32x4 s1 = __builtin_amdgcn_mfma_f32_16x16x32_bf16(KF, qf1, zero,   \
                                                             0, 0, 0);        \
    union { ushort u[4]; uint2 v; } pk0, pk1;                                 \
    _Pragma("unroll")                                                         \
    for (int r = 0; r < 4; ++r) {                                             \
      const float e0 = exp2f(s0[r]);                                          \
      const float e1 = exp2f(s1[r]);                                          \
      lp0 += e0; lp1 += e1;                                                   \
      pk0.u[r] = f2bf(e0); pk1.u[r] = f2bf(e1);                               \
    }                                                                         \
    *(uint2*)&Pb[PIDX(prow0, (COL) + g16 * 4)] = pk0.v;                       \
    *(uint2*)&Pb[PIDX(prow1, (COL) + g16 * 4)] = pk1.v;                       \
  } while (0)

// compute S_JT on slot JT at column COL, then reload slot JT from j-row RJ
#define S_JTR(JT, COL, RJ)                                                    \
  do {                                                                        \
    S_JT(kf[JT], COL);                                                        \
    kf[JT] = *(const short8*)(kbase + (size_t)((RJ) + (JT) * 16 + c16) * 64); \
  } while (0)

  if (isS) {
    qf0 = *(const short8*)(qk + ((size_t)(b * NN + i0 + prow0)) * 64 + g16 * 8);
    qf1 = *(const short8*)(qk + ((size_t)(b * NN + i0 + prow1)) * 64 + g16 * 8);
#pragma unroll
    for (int jt = 0; jt < 8; ++jt)   // prologue: chunk 0 half0
      kf[jt] = *(const short8*)(kbase + (size_t)(jt * 16 + c16) * 64);
  }

  // ---- PV state (waves 4-11): 32 channels x 128 rows ----
  const int p = w - 4;                   // 0..7
  f32x16 OA[4];
  const ushort* vptr = nullptr;
  short8 vf[2];
  if (!isS) {
#pragma unroll
    for (int isub = 0; isub < 4; ++isub)
#pragma unroll
      for (int e = 0; e < 16; ++e) OA[isub][e] = 0.f;
    vptr = vt + ((size_t)(b * NC + p * 32 + c32)) * NN + l5 * 8;
  }

#define PVC(VF, JI)                                                           \
  do {                                                                        \
    const int jo = (JI) * 16;                                                 \
    _Pragma("unroll")                                                         \
    for (int isub = 0; isub < 4; ++isub) {                                    \
      const short8 pa =                                                       \
          *(const short8*)&Pb[PIDX(isub * 32 + c32, jo + l5 * 8)];            \
      OA[isub] = __builtin_amdgcn_mfma_f32_32x32x16_bf16(                     \
          pa, VF, OA[isub], 0, 0, 0);                                         \
    }                                                                         \
  } while (0)

  for (int iv = 0; iv <= NCH; ++iv) {
    if (isS) {
      if (iv < NCH) {
        ushort* Pb = P[iv & 1];
        const int j0 = iv * 256;
        const int jh1 = j0 + 128;                       // this chunk, half1
        const int jn  = (iv + 1 < NCH) ? (j0 + 256) : 0; // next chunk half0
        // half0 compute, rotating in half1
        S_JTR(0, 0, jh1);   S_JTR(1, 16, jh1);  S_JTR(2, 32, jh1);
        S_JTR(3, 48, jh1);  S_JTR(4, 64, jh1);  S_JTR(5, 80, jh1);
        S_JTR(6, 96, jh1);  S_JTR(7, 112, jh1);
        // half1 compute, rotating in next chunk's half0 (crosses barrier)
        S_JTR(0, 128, jn);  S_JTR(1, 144, jn);  S_JTR(2, 160, jn);
        S_JTR(3, 176, jn);  S_JTR(4, 192, jn);  S_JTR(5, 208, jn);
        S_JTR(6, 224, jn);  S_JTR(7, 240, jn);
      } else {
        // interval 16: finalize row sums (reduce over the 4 g16 groups)
        lp0 += __shfl_xor(lp0, 16); lp0 += __shfl_xor(lp0, 32);
        lp1 += __shfl_xor(lp1, 16); lp1 += __shfl_xor(lp1, 32);
        if (g16 == 0) { lL[prow0] = lp0; lL[prow1] = lp1; }
      }
    } else {
      if (iv == 0) {
        // preload chunk 0's first two V fragments (drain at barrier, free)
        vf[0] = *(const short8*)(vptr + 0);
        vf[1] = *(const short8*)(vptr + 16);
      } else {
        const int ch = iv - 1;
        const ushort* Pb = P[ch & 1];
        const int j0 = ch * 256;
        __builtin_amdgcn_s_setprio(1);
#pragma unroll
        for (int ji = 0; ji < 16; ++ji) {
          const short8 v0 = vf[ji & 1];
          // refill this slot with step ji+2 (wrapped uniform offset; for
          // ji=14,15 this is the NEXT chunk's steps 0,1 — or chunk 0's when
          // ch==15, harmless: issued, never consumed)
          vf[ji & 1] =
              *(const short8*)(vptr + ((j0 + (ji + 2) * 16) & (NN - 1)));
          PVC(v0, ji);
        }
        __builtin_amdgcn_s_setprio(0);
      }
    }
    __syncthreads();
  }

  // ---- epilogue: PV waves write out = gamma*O/l + x ----
  if (!isS) {
    const float g = gamma[0];
#pragma unroll
    for (int isub = 0; isub < 4; ++isub) {
#pragma unroll
      for (int q = 0; q < 4; ++q) {
        const int r0 = isub * 32 + q * 8 + l5 * 4;   // D row: (reg&3)+8q+4*l5
        const f32x4 li = *(const f32x4*)&lL[r0];
        f32x4 gi;
#pragma unroll
        for (int r = 0; r < 4; ++r) gi[r] = g / li[r];
        const int c = p * 32 + c32;
        const size_t base = ((size_t)(b * NC + c)) * NN + i0 + r0;
        const f32x4 xv = *(const f32x4*)(x + base);
        f32x4 ov;
#pragma unroll
        for (int r = 0; r < 4; ++r) ov[r] = OA[isub][q * 4 + r] * gi[r] + xv[r];
        *(f32x4*)(out + base) = ov;
      }
    }
  }
}

extern "C" void kernel_launch(void* const* d_in, const int* in_sizes, int n_in,
                              void* d_out, int out_size, void* d_ws, size_t ws_size,
                              hipStream_t stream) {
  const float* x  = (const float*)d_in[0];
  const float* wq = (const float*)d_in[1];
  const float* bq = (const float*)d_in[2];
  const float* wk = (const float*)d_in[3];
  const float* bk = (const float*)d_in[4];
  const float* wv = (const float*)d_in[5];
  const float* bv = (const float*)d_in[6];
  const float* gm = (const float*)d_in[7];
  float* outp = (float*)d_out;

  ushort* qkw = (ushort*)d_ws;                       // [B][N][64]  bf16, 4 MB
  ushort* vtw = qkw + (size_t)NB * NN * 64;          // [B][C][N]   bf16, 16 MB

  proj_kernel<<<dim3(NN / 128, 5, NB), 256, 0, stream>>>(
      x, wq, bq, wk, bk, wv, bv, qkw, vtw);
  attn_kernel<<<dim3((NN / 128) * NB), 768, 0, stream>>>(qkw, vtw, x, gm, outp);
}

// Round 22
// 150.532 us; speedup vs baseline: 2.3303x; 2.3303x over previous
//
#include <hip/hip_runtime.h>
#include <hip/hip_bf16.h>

typedef __attribute__((ext_vector_type(8))) short short8;   // 8 bf16 (4 VGPRs)
typedef __attribute__((ext_vector_type(4))) float f32x4;    // MFMA 16x16 C/D
typedef __attribute__((ext_vector_type(16))) float f32x16;  // MFMA 32x32 C/D

#define NB 8
#define NC 256
#define NN 4096
#define ND 32
#define NCH 16   // attn j-chunks of 256
#define LOG2E 1.44269504088896340736f

// attn P tile [2][128][256] ushort, 16B-slot XOR swizzle (validated R8/R10).
#define PIDX(row, col) (((row) << 8) + ((col) ^ (((row) & 15) << 3)))

static __device__ __forceinline__ ushort f2bf(float f) {
  __hip_bfloat16 h = __float2bfloat16(f);
  return reinterpret_cast<ushort&>(h);
}
static __device__ __forceinline__ float bf2f(ushort u) {
  const uint v = ((uint)u) << 16;
  return __builtin_bit_cast(float, v);
}

// ---------------------------------------------------------------------------
// Projection via MFMA — R16 VERBATIM (validated: fast, absmax 0.125).
// ---------------------------------------------------------------------------
#define LDW 264   // Ws row stride (ushorts)
#define LDX 40    // Xs row stride (ushorts)
#define LDO 136   // Os row stride (ushorts)

__global__ __launch_bounds__(256, 2)
void proj_kernel(const float* __restrict__ x,
                 const float* __restrict__ wq, const float* __restrict__ bq,
                 const float* __restrict__ wk, const float* __restrict__ bk,
                 const float* __restrict__ wv, const float* __restrict__ bv,
                 ushort* __restrict__ qk, ushort* __restrict__ vt) {
  __shared__ __align__(16) ushort Ws[2][64 * LDW];   // 67.6 KB
  __shared__ __align__(16) ushort Xs[128 * LDX];     // 10.2 KB

  const int n0 = blockIdx.x * 128;
  const int o0 = blockIdx.y * 64;
  const int b  = blockIdx.z;
  const int t  = threadIdx.x;
  const int w  = t >> 6;
  const int lane = t & 63;
  const int g16  = lane >> 4;
  const int c16  = lane & 15;

  {
    const int o  = t >> 2;
    const int cb = (t & 3) * 64;
    const int oa = o0 + o;
    const float* wrow;
    float scale = 1.0f;
    if (oa < 32)       { wrow = wq + (size_t)oa * NC; scale = LOG2E; }
    else if (oa < 64)  { wrow = wk + (size_t)(oa - 32) * NC; }
    else               { wrow = wv + (size_t)(oa - 64) * NC; }
#pragma unroll
    for (int cc = 0; cc < 64; cc += 8) {
      const float4 f0 = *(const float4*)(wrow + cb + cc);
      const float4 f1 = *(const float4*)(wrow + cb + cc + 4);
      float v[8] = {f0.x, f0.y, f0.z, f0.w, f1.x, f1.y, f1.z, f1.w};
      union { ushort u[8]; uint4 q; } hi, lo;
#pragma unroll
      for (int e = 0; e < 8; ++e) {
        const float s = v[e] * scale;
        const ushort h = f2bf(s);
        hi.u[e] = h;
        lo.u[e] = f2bf(s - bf2f(h));
      }
      *(uint4*)&Ws[0][o * LDW + cb + cc] = hi.q;
      *(uint4*)&Ws[1][o * LDW + cb + cc] = lo.q;
    }
  }

  f32x4 acc[8];
#pragma unroll
  for (int nt = 0; nt < 8; ++nt)
#pragma unroll
    for (int r = 0; r < 4; ++r) acc[nt][r] = 0.f;

  const int s_cc = w * 8 + (lane >> 3);
  const int s_nb = (lane & 7) * 4;

  for (int c0 = 0; c0 < NC; c0 += 32) {
    __syncthreads();
    {
      const float* xsrc = x + ((size_t)(b * NC + c0 + s_cc)) * NN + n0 + s_nb;
#pragma unroll
      for (int it = 0; it < 4; ++it) {
        const float4 f = *(const float4*)(xsrc + it * 32);
        const int n = s_nb + it * 32;
        Xs[(n + 0) * LDX + s_cc] = f2bf(f.x);
        Xs[(n + 1) * LDX + s_cc] = f2bf(f.y);
        Xs[(n + 2) * LDX + s_cc] = f2bf(f.z);
        Xs[(n + 3) * LDX + s_cc] = f2bf(f.w);
      }
    }
    __syncthreads();

    const short8 ah = *(const short8*)&Ws[0][(w * 16 + c16) * LDW + c0 + g16 * 8];
    const short8 al = *(const short8*)&Ws[1][(w * 16 + c16) * LDW + c0 + g16 * 8];
#pragma unroll
    for (int nt = 0; nt < 8; ++nt) {
      const short8 bf = *(const short8*)&Xs[(nt * 16 + c16) * LDX + g16 * 8];
      acc[nt] = __builtin_amdgcn_mfma_f32_16x16x32_bf16(ah, bf, acc[nt], 0, 0, 0);
      acc[nt] = __builtin_amdgcn_mfma_f32_16x16x32_bf16(al, bf, acc[nt], 0, 0, 0);
    }
  }

  if (blockIdx.y == 0) {
    float bb[4];
#pragma unroll
    for (int r = 0; r < 4; ++r) {
      const int o = w * 16 + g16 * 4 + r;
      bb[r] = (o < 32) ? bq[o] * LOG2E : bk[o - 32];
    }
#pragma unroll
    for (int nt = 0; nt < 8; ++nt) {
      union { ushort u[4]; uint2 v; } pk;
#pragma unroll
      for (int r = 0; r < 4; ++r) pk.u[r] = f2bf(acc[nt][r] + bb[r]);
      const int n = n0 + nt * 16 + c16;
      *(uint2*)(qk + ((size_t)(b * NN + n)) * 64 + w * 16 + g16 * 4) = pk.v;
    }
  } else {
    const int ch0 = o0 - 64;
    float bb[4];
#pragma unroll
    for (int r = 0; r < 4; ++r) bb[r] = bv[ch0 + w * 16 + g16 * 4 + r];
    __syncthreads();
    ushort* Os = &Ws[0][0];
#pragma unroll
    for (int nt = 0; nt < 8; ++nt) {
#pragma unroll
      for (int r = 0; r < 4; ++r)
        Os[(w * 16 + g16 * 4 + r) * LDO + nt * 16 + c16] =
            f2bf(acc[nt][r] + bb[r]);
    }
    __syncthreads();
    const int chl = t >> 2;
    const int nb  = (t & 3) * 32;
    ushort* dst = vt + ((size_t)(b * NC + ch0 + chl)) * NN + n0 + nb;
#pragma unroll
    for (int k = 0; k < 4; ++k)
      *(uint4*)(dst + k * 8) = *(const uint4*)&Os[chl * LDO + nb + k * 8];
  }
}

// ---------------------------------------------------------------------------
// Flash attention: R18 VERBATIM except PV's V rotation is refilled 2 steps
// ahead (same 2 slots, same names, same liveness width — allocation-identical
// frame expected). Within-chunk only: prologue loads steps 0,1; refill
// vf[ji&1] <- V(ji+2) for ji<14; steps 14,15 consume without refill; next
// chunk starts with a fresh 2-load prologue (one ~300cy wait per chunk).
// 256 blocks x 768 threads, 3 waves/SIMD (1 S + 2 PV).
// ---------------------------------------------------------------------------
__global__ __launch_bounds__(768, 3)
void attn_kernel(const ushort* __restrict__ qk, const ushort* __restrict__ vt,
                 const float* __restrict__ x, const float* __restrict__ gamma,
                 float* __restrict__ out) {
  __shared__ __align__(16) ushort P[2][128 * 256];   // 128 KB, swizzled
  __shared__ __align__(16) float lL[128];

  const int lin  = blockIdx.x;
  const int b    = lin & 7;              // XCD swizzle: batch per XCD L2
  const int i0   = (lin >> 3) * 128;
  const int t    = threadIdx.x;
  const int w    = t >> 6;               // 0..11
  const int lane = t & 63;
  const int g16  = lane >> 4;
  const int c16  = lane & 15;
  const int l5   = lane >> 5;
  const int c32  = lane & 31;

  const f32x4 zero = {0.f, 0.f, 0.f, 0.f};
  const bool isS = (w < 4);

  // ---- S state (waves 0-3): 32 q-rows each (R18/R10 verbatim) ----
  const int prow0 = w * 32 + c16;
  const int prow1 = prow0 + 16;
  short8 qf0, qf1;
  short8 kf[8];
  float lp0 = 0.f, lp1 = 0.f;
  const ushort* kbase = qk + ((size_t)b * NN) * 64 + 32 + g16 * 8;
  if (isS) {
    qf0 = *(const short8*)(qk + ((size_t)(b * NN + i0 + prow0)) * 64 + g16 * 8);
    qf1 = *(const short8*)(qk + ((size_t)(b * NN + i0 + prow1)) * 64 + g16 * 8);
  }

  // ---- PV state (waves 4-11): 32 channels x 128 rows ----
  const int p = w - 4;                   // 0..7
  f32x16 OA[4];
  const ushort* vptr = nullptr;
  if (!isS) {
#pragma unroll
    for (int isub = 0; isub < 4; ++isub)
#pragma unroll
      for (int e = 0; e < 16; ++e) OA[isub][e] = 0.f;
    vptr = vt + ((size_t)(b * NC + p * 32 + c32)) * NN + l5 * 8;
  }

  for (int iv = 0; iv <= NCH; ++iv) {
    if (isS) {
      if (iv < NCH) {
        ushort* Pb = P[iv & 1];
        const ushort* kch = kbase + (size_t)iv * 256 * 64;
#pragma unroll
        for (int h = 0; h < 2; ++h) {
#pragma unroll
          for (int jt = 0; jt < 8; ++jt)
            kf[jt] = *(const short8*)(
                kch + (size_t)(h * 128 + jt * 16 + c16) * 64);
#pragma unroll
          for (int jt = 0; jt < 8; ++jt) {
            const f32x4 s0 = __builtin_amdgcn_mfma_f32_16x16x32_bf16(
                kf[jt], qf0, zero, 0, 0, 0);
            const f32x4 s1 = __builtin_amdgcn_mfma_f32_16x16x32_bf16(
                kf[jt], qf1, zero, 0, 0, 0);
            union { ushort u[4]; uint2 v; } pk0, pk1;
#pragma unroll
            for (int r = 0; r < 4; ++r) {
              const float e0 = exp2f(s0[r]);
              const float e1 = exp2f(s1[r]);
              lp0 += e0; lp1 += e1;
              pk0.u[r] = f2bf(e0); pk1.u[r] = f2bf(e1);
            }
            const int col = h * 128 + jt * 16 + g16 * 4;
            *(uint2*)&Pb[PIDX(prow0, col)] = pk0.v;
            *(uint2*)&Pb[PIDX(prow1, col)] = pk1.v;
          }
        }
      } else {
        lp0 += __shfl_xor(lp0, 16); lp0 += __shfl_xor(lp0, 32);
        lp1 += __shfl_xor(lp1, 16); lp1 += __shfl_xor(lp1, 32);
        if (g16 == 0) { lL[prow0] = lp0; lL[prow1] = lp1; }
      }
    } else if (iv >= 1) {
      const int ch = iv - 1;
      const ushort* Pb = P[ch & 1];
      const int j0 = ch * 256;
      // 2-slot V rotation, refilled 2 steps ahead (within-chunk only)
      short8 vf[2];
      vf[0] = *(const short8*)(vptr + j0);
      vf[1] = *(const short8*)(vptr + j0 + 16);
      __builtin_amdgcn_s_setprio(1);
#pragma unroll
      for (int ji = 0; ji < 16; ++ji) {
        const short8 v0 = vf[ji & 1];
        if (ji < 14)
          vf[ji & 1] = *(const short8*)(vptr + j0 + (ji + 2) * 16);
        const int jo = ji * 16;
#pragma unroll
        for (int isub = 0; isub < 4; ++isub) {
          const short8 pa =
              *(const short8*)&Pb[PIDX(isub * 32 + c32, jo + l5 * 8)];
          OA[isub] = __builtin_amdgcn_mfma_f32_32x32x16_bf16(
              pa, v0, OA[isub], 0, 0, 0);
        }
      }
      __builtin_amdgcn_s_setprio(0);
    }
    __syncthreads();
  }

  // ---- epilogue: PV waves write out = gamma*O/l + x ----
  if (!isS) {
    const float g = gamma[0];
#pragma unroll
    for (int isub = 0; isub < 4; ++isub) {
#pragma unroll
      for (int q = 0; q < 4; ++q) {
        const int r0 = isub * 32 + q * 8 + l5 * 4;   // D row: (reg&3)+8q+4*l5
        const f32x4 li = *(const f32x4*)&lL[r0];
        f32x4 gi;
#pragma unroll
        for (int r = 0; r < 4; ++r) gi[r] = g / li[r];
        const int c = p * 32 + c32;
        const size_t base = ((size_t)(b * NC + c)) * NN + i0 + r0;
        const f32x4 xv = *(const f32x4*)(x + base);
        f32x4 ov;
#pragma unroll
        for (int r = 0; r < 4; ++r) ov[r] = OA[isub][q * 4 + r] * gi[r] + xv[r];
        *(f32x4*)(out + base) = ov;
      }
    }
  }
}

extern "C" void kernel_launch(void* const* d_in, const int* in_sizes, int n_in,
                              void* d_out, int out_size, void* d_ws, size_t ws_size,
                              hipStream_t stream) {
  const float* x  = (const float*)d_in[0];
  const float* wq = (const float*)d_in[1];
  const float* bq = (const float*)d_in[2];
  const float* wk = (const float*)d_in[3];
  const float* bk = (const float*)d_in[4];
  const float* wv = (const float*)d_in[5];
  const float* bv = (const float*)d_in[6];
  const float* gm = (const float*)d_in[7];
  float* outp = (float*)d_out;

  ushort* qkw = (ushort*)d_ws;                       // [B][N][64]  bf16, 4 MB
  ushort* vtw = qkw + (size_t)NB * NN * 64;          // [B][C][N]   bf16, 16 MB

  proj_kernel<<<dim3(NN / 128, 5, NB), 256, 0, stream>>>(
      x, wq, bq, wk, bk, wv, bv, qkw, vtw);
  attn_kernel<<<dim3((NN / 128) * NB), 768, 0, stream>>>(qkw, vtw, x, gm, outp);
}